// Round 6
// baseline (3964.128 us; speedup 1.0000x reference)
//
#include <hip/hip_runtime.h>
#include <stdint.h>

#define LN2F 0.69314718055994530942f

// ---------------- Threefry-2x32 (20 rounds), exactly JAX's schedule ----------------
__device__ __forceinline__ uint32_t rotl32(uint32_t x, int r){ return (x<<r)|(x>>(32-r)); }

__device__ __forceinline__ void tf2x32(uint32_t ks0, uint32_t ks1, uint32_t ks2,
                                       uint32_t x0, uint32_t x1,
                                       uint32_t &o0, uint32_t &o1){
  x0 += ks0; x1 += ks1;
#define TF_R4(a,b,c,d) \
  x0+=x1; x1=rotl32(x1,a); x1^=x0; \
  x0+=x1; x1=rotl32(x1,b); x1^=x0; \
  x0+=x1; x1=rotl32(x1,c); x1^=x0; \
  x0+=x1; x1=rotl32(x1,d); x1^=x0;
  TF_R4(13,15,26,6);  x0+=ks1; x1+=ks2+1u;
  TF_R4(17,29,16,24); x0+=ks2; x1+=ks0+2u;
  TF_R4(13,15,26,6);  x0+=ks0; x1+=ks1+3u;
  TF_R4(17,29,16,24); x0+=ks1; x1+=ks2+4u;
  TF_R4(13,15,26,6);  x0+=ks2; x1+=ks0+5u;
#undef TF_R4
  o0=x0; o1=x1;
}

// ---------------- Layer 1: h1 = relu(y @ W1 + b1), (16384x10)x(10x128) -------------
__global__ __launch_bounds__(256) void mlp1_kernel(
    const float* __restrict__ y, const float* __restrict__ W1,
    const float* __restrict__ b1, float* __restrict__ h1){
  int idx = blockIdx.x*256 + threadIdx.x;   // 16384*128 elements
  int r = idx >> 7, c = idx & 127;
  float acc = b1[c];
#pragma unroll
  for (int k=0;k<10;k++) acc = fmaf(y[r*10+k], W1[k*128+c], acc);
  h1[idx] = fmaxf(acc, 0.f);
}

// ---------------- Generic f32 tiled GEMM + bias + relu -----------------------------
__global__ __launch_bounds__(256) void gemm_relu_kernel(
    const float* __restrict__ A, const float* __restrict__ B,
    const float* __restrict__ bias, float* __restrict__ C,
    int N, int K){
  __shared__ float As[64][33];
  __shared__ float Bs[32][64];
  const int tid = threadIdx.x;
  const int tx = tid & 15, ty = tid >> 4;
  const int r0 = blockIdx.y*64, c0 = blockIdx.x*64;
  float acc[4][4] = {};
  for (int k0=0; k0<K; k0+=32){
#pragma unroll
    for (int i=0;i<8;i++){
      int flat = tid + i*256;
      int ar = flat>>5, ac = flat&31;
      As[ar][ac] = A[(size_t)(r0+ar)*K + (k0+ac)];
    }
#pragma unroll
    for (int i=0;i<8;i++){
      int flat = tid + i*256;
      int br = flat>>6, bc = flat&63;
      int gc = c0+bc;
      Bs[br][bc] = (gc<N) ? B[(size_t)(k0+br)*N + gc] : 0.f;
    }
    __syncthreads();
#pragma unroll
    for (int kk=0;kk<32;kk++){
      float a0=As[ty*4+0][kk], a1=As[ty*4+1][kk], a2=As[ty*4+2][kk], a3=As[ty*4+3][kk];
      float4 b = *(const float4*)&Bs[kk][tx*4];
      acc[0][0]=fmaf(a0,b.x,acc[0][0]); acc[0][1]=fmaf(a0,b.y,acc[0][1]);
      acc[0][2]=fmaf(a0,b.z,acc[0][2]); acc[0][3]=fmaf(a0,b.w,acc[0][3]);
      acc[1][0]=fmaf(a1,b.x,acc[1][0]); acc[1][1]=fmaf(a1,b.y,acc[1][1]);
      acc[1][2]=fmaf(a1,b.z,acc[1][2]); acc[1][3]=fmaf(a1,b.w,acc[1][3]);
      acc[2][0]=fmaf(a2,b.x,acc[2][0]); acc[2][1]=fmaf(a2,b.y,acc[2][1]);
      acc[2][2]=fmaf(a2,b.z,acc[2][2]); acc[2][3]=fmaf(a2,b.w,acc[2][3]);
      acc[3][0]=fmaf(a3,b.x,acc[3][0]); acc[3][1]=fmaf(a3,b.y,acc[3][1]);
      acc[3][2]=fmaf(a3,b.z,acc[3][2]); acc[3][3]=fmaf(a3,b.w,acc[3][3]);
    }
    __syncthreads();
  }
#pragma unroll
  for (int i=0;i<4;i++){
    int r = r0 + ty*4 + i;
#pragma unroll
    for (int j=0;j<4;j++){
      int c = c0 + tx*4 + j;
      if (c < N) C[(size_t)r*N + c] = fmaxf(acc[i][j] + bias[c], 0.f);
    }
  }
}

// ---------------- Reparametrize (partitionable threefry) ---------------------------
// keys[s] = cipher(key=(0,1), x=(0,s)); bits[e] = o0^o1 of cipher(key_s, x=(0,e)).
// One wave per row, 13 col-registers/lane. All math in log2 domain:
// zb = 10*log2(p) - 10*log2(-ln u); softmax = exp2(zb - max)/sum.
// -ln u via degree-7 log1p poly for u>0.875 (hw v_log is abs-error-bounded near 1,
// which would put O(1) relative error on the winning gumbels).
__global__ __launch_bounds__(256) void reparam_kernel(
    const float* __restrict__ proba, float* __restrict__ img){
  __shared__ uint32_t skeys[256];
  const int tid = threadIdx.x;
  if (tid < 128){
    uint32_t y0,y1;
    // root key(1) = (0,1): ks2 = 0^1^0x1BD11BDA
    tf2x32(0u, 1u, 0x1BD11BDBu, 0u, (uint32_t)tid, y0, y1);
    skeys[2*tid] = y0; skeys[2*tid+1] = y1;
  }
  __syncthreads();

  const int lane = tid & 63;
  const int wv   = tid >> 6;
  const int row  = blockIdx.x*4 + wv;      // 0..16383
  const float* pr = proba + (size_t)row*784;

  float lp[13], acc[13];
#pragma unroll
  for (int m=0;m<13;m++){
    int c = lane + 64*m;
    bool v = (m<12) || (lane<16);
    float a = v ? pr[c] : 1.f;
    lp[m] = 10.f*__builtin_amdgcn_logf(a);   // 10*log2(p)
    acc[m] = 0.f;
  }

  const uint32_t ebase = (uint32_t)row*784u + (uint32_t)lane;

  for (int s=0;s<128;s++){
    uint32_t k0 = skeys[2*s], k1 = skeys[2*s+1];
    uint32_t k2 = k0 ^ k1 ^ 0x1BD11BDAu;
    float zb[13];
    float mx = -INFINITY;
#pragma unroll
    for (int m=0;m<13;m++){
      uint32_t o0,o1;
      tf2x32(k0,k1,k2, 0u, ebase + 64u*(uint32_t)m, o0,o1);
      uint32_t bits = o0 ^ o1;
      float u = __uint_as_float((bits>>9) | 0x3F800000u) - 1.f;   // JAX uniform [0,1)
      // w = -ln(u): poly path for u near 1 (t = u-1 exact)
      float t = u - 1.f;
      float P = fmaf(t, 1.f/7.f, -1.f/6.f);
      P = fmaf(t, P, 1.f/5.f);
      P = fmaf(t, P, -1.f/4.f);
      P = fmaf(t, P, 1.f/3.f);
      P = fmaf(t, P, -1.f/2.f);
      P = fmaf(t, P, 1.f);
      float w_poly = -t*P;
      float w_hw = -LN2F*__builtin_amdgcn_logf(u);   // u=0 -> +inf (g=-inf) ok
      float w = (u > 0.875f) ? w_poly : w_hw;
      float z = fmaf(-10.f, __builtin_amdgcn_logf(w), lp[m]);
      if (m==12 && lane>=16) z = -INFINITY;
      zb[m]=z;
      mx = fmaxf(mx,z);
    }
#pragma unroll
    for (int off=1; off<64; off<<=1)
      mx = fmaxf(mx, __shfl_xor(mx, off, 64));
    float ssum=0.f;
#pragma unroll
    for (int m=0;m<13;m++){
      float e2 = __builtin_amdgcn_exp2f(zb[m]-mx);
      zb[m]=e2; ssum+=e2;
    }
#pragma unroll
    for (int off=1; off<64; off<<=1)
      ssum += __shfl_xor(ssum, off, 64);
    float rs = __builtin_amdgcn_rcpf(ssum);
#pragma unroll
    for (int m=0;m<13;m++) acc[m] = fmaf(zb[m], rs, acc[m]);
  }

  float* op = img + (size_t)row*784;
#pragma unroll
  for (int m=0;m<13;m++){
    int c = lane + 64*m;
    if (m<12 || lane<16) op[c]=acc[m];
  }
}

// -----------------------------------------------------------------------------------
extern "C" void kernel_launch(void* const* d_in, const int* in_sizes, int n_in,
                              void* d_out, int out_size, void* d_ws, size_t ws_size,
                              hipStream_t stream){
  const float* y  = (const float*)d_in[0];
  const float* W1 = (const float*)d_in[1];
  const float* b1 = (const float*)d_in[2];
  const float* W2 = (const float*)d_in[3];
  const float* b2 = (const float*)d_in[4];
  const float* W3 = (const float*)d_in[5];
  const float* b3 = (const float*)d_in[6];

  float* img   = (float*)d_out;                       // 16384*784
  float* proba = (float*)d_out + (size_t)16384*784;   // 16384*784

  // h1/h2 scratch in the img half of d_out (dead until reparam overwrites it):
  float* h1 = img;
  float* h2 = img + (size_t)16384*128;

  mlp1_kernel<<<8192, 256, 0, stream>>>(y, W1, b1, h1);
  gemm_relu_kernel<<<dim3(8, 256), 256, 0, stream>>>(h1, W2, b2, h2, 512, 128);
  gemm_relu_kernel<<<dim3(13, 256), 256, 0, stream>>>(h2, W3, b3, proba, 784, 512);
  reparam_kernel<<<4096, 256, 0, stream>>>(proba, img);
}